// Round 5
// baseline (313.911 us; speedup 1.0000x reference)
//
#include <hip/hip_runtime.h>
#include <math.h>

#define HDIM 256
#define PDIM 256
#define BATCH 8
#define LSEQ 4096
#define MTOT (BATCH * LSEQ)   // 32768
#define CHLEN 128             // chunk = one 128-row M-tile
#define NCHUNK 32             // LSEQ / CHLEN
#define HSTR 264              // padded LDS row stride (bf16 elems), 16B-aligned

typedef __attribute__((ext_vector_type(8))) short bf16x8;   // 8 bf16 = 4 VGPRs
typedef __attribute__((ext_vector_type(4))) float f32x4;
typedef unsigned long long ull;

__device__ __forceinline__ unsigned short f2bf(float f) {
    union { float f; unsigned int u; } v; v.f = f;
    unsigned int r = v.u + 0x7FFFu + ((v.u >> 16) & 1u);   // RNE
    return (unsigned short)(r >> 16);
}
__device__ __forceinline__ float bf2f(unsigned int lo16) {
    union { unsigned int u; float f; } v; v.u = lo16 << 16;
    return v.f;
}

// ---------------- params: par=a, apw[j][2p]=a^{j+1} (j<128), Apow[m][2p]=a^{128m} (m<32) ----------------
__global__ void params_k(const float* __restrict__ llr, const float* __restrict__ lim,
                         const float* __restrict__ ldl, float* __restrict__ par,
                         float* __restrict__ apw, float* __restrict__ Apow) {
    int p = threadIdx.x;
    float er = expf(llr[p]);          // -Re(lam) > 0
    float im = lim[p];
    float d  = expf(ldl[p]);
    float zr = -er * d, zi = im * d;  // lam*delta
    float ea = expf(zr);
    float ar = ea * cosf(zi), ai = ea * sinf(zi);   // a = exp(lam*delta)
    par[2 * p]     = ar;
    par[2 * p + 1] = ai;
    float pr = ar, pi = ai;
    apw[2 * p] = pr; apw[2 * p + 1] = pi;           // a^1
    for (int j = 1; j < CHLEN; j++) {
        float nr = pr * ar - pi * ai;
        float ni = pr * ai + pi * ar;
        pr = nr; pi = ni;
        apw[j * 512 + 2 * p]     = pr;              // a^{j+1}
        apw[j * 512 + 2 * p + 1] = pi;
    }
    // pr,pi == a^128 now
    float A128r = pr, A128i = pi;
    float cr = 1.0f, ci = 0.0f;
    Apow[2 * p] = 1.0f; Apow[2 * p + 1] = 0.0f;     // m=0 -> identity
    for (int m = 1; m < 32; m++) {
        float nr = cr * A128r - ci * A128i;
        float ni = cr * A128i + ci * A128r;
        cr = nr; ci = ni;
        Apow[m * 512 + 2 * p]     = cr;
        Apow[m * 512 + 2 * p + 1] = ci;
    }
}

// W1t[n][k] (bf16 [512][256]): n=2p -> Re(coef_p*B[p][k]), n=2p+1 -> Im.
// W2t[h][2p] = Cr[h][p]; W2t[h][2p+1] = -Ci[h][p]  (bf16 [256][512]).
__global__ void w12_k(const float* __restrict__ Br, const float* __restrict__ Bi,
                      const float* __restrict__ Cr, const float* __restrict__ Ci,
                      const float* __restrict__ llr, const float* __restrict__ lim,
                      const float* __restrict__ ldl,
                      unsigned short* __restrict__ W1t, unsigned short* __restrict__ W2t) {
    int p = blockIdx.x, h = threadIdx.x;
    float er = expf(llr[p]);
    float im = lim[p];
    float d  = expf(ldl[p]);
    float zr = -er * d, zi = im * d;
    float ea = expf(zr);
    float ar = ea * cosf(zi), ai = ea * sinf(zi);
    float dr = -er, di = im;
    float den = dr * dr + di * di;
    float nr = ar - 1.0f, ni = ai;
    float cr = (nr * dr + ni * di) / den;           // coef = (a-1)/lam
    float ci = (ni * dr - nr * di) / den;
    float br = Br[p * HDIM + h], bi = Bi[p * HDIM + h];
    W1t[(2 * p) * HDIM + h]     = f2bf(cr * br - ci * bi);
    W1t[(2 * p + 1) * HDIM + h] = f2bf(cr * bi + ci * br);
    W2t[h * 512 + 2 * p]     = f2bf(Cr[h * PDIM + p]);
    W2t[h * 512 + 2 * p + 1] = f2bf(-Ci[h * PDIM + p]);
}

// ---------------- fully-fused persistent block kernel: 256 blocks = 1 per CU ----------------
__launch_bounds__(512, 1)
__global__ void fused_k(const float* __restrict__ u,
                        const unsigned short* __restrict__ W1t,
                        const unsigned short* __restrict__ W2t,
                        const float* __restrict__ par, const float* __restrict__ apw,
                        const float* __restrict__ Apow,
                        ull* __restrict__ Lbuf, int* __restrict__ flags,
                        const float* __restrict__ gamma, const float* __restrict__ beta_p,
                        float* __restrict__ out) {
    __shared__ unsigned short hS[128 * HSTR];   // 67.6 KB: LN'd input tile (bf16)
    __shared__ unsigned short BuS[128 * HSTR];  // 67.6 KB: Bu/x half-tile (bf16)
    __shared__ float2 Pp[128];                  // chunk-entry prefix per complex col

    const int t = threadIdx.x;
    const int blk = blockIdx.x;            // 0..255  = b*32 + c
    const int b = blk >> 5, c = blk & 31;
    const int w = t >> 6, lane = t & 63;
    const size_t rowbase = (size_t)blk * 128;

    const int mrow = lane & 15, kq = (lane >> 4) * 8;
    const int r0 = (lane >> 4) * 4, c0 = lane & 15;
    const int wm1 = (w & 1) * 64, wn1 = (w >> 1) * 32;   // GEMM1: wave = 64m x 32n
    const int wm2 = (w & 1) * 64, wn2 = (w >> 1) * 64;   // GEMM2: wave = 64m x 64n

    // ---- Phase A: LayerNorm u-tile -> hS (bf16) ----
    {
        const int cidx = lane * 4;
        float4 g4 = *(const float4*)(gamma + cidx);
        float4 b4 = *(const float4*)(beta_p + cidx);
        const int rw = w * 16;
        for (int it = 0; it < 16; ++it) {
            int row = rw + it;
            float4 v = *(const float4*)(u + (rowbase + row) * 256 + cidx);
            float s  = v.x + v.y + v.z + v.w;
            float sq = v.x * v.x + v.y * v.y + v.z * v.z + v.w * v.w;
            #pragma unroll
            for (int o = 1; o < 64; o <<= 1) { s += __shfl_xor(s, o); sq += __shfl_xor(sq, o); }
            float mu = s * (1.0f / 256.0f);
            float rs = rsqrtf(sq * (1.0f / 256.0f) - mu * mu + 1e-5f);
            unsigned int w0 = (unsigned int)f2bf((v.x - mu) * rs * g4.x + b4.x)
                            | ((unsigned int)f2bf((v.y - mu) * rs * g4.y + b4.y) << 16);
            unsigned int w1 = (unsigned int)f2bf((v.z - mu) * rs * g4.z + b4.z)
                            | ((unsigned int)f2bf((v.w - mu) * rs * g4.w + b4.w) << 16);
            *(uint2*)&hS[row * HSTR + cidx] = make_uint2(w0, w1);
        }
    }
    __syncthreads();

    f32x4 acc2[4][4] = {};
    unsigned int* BuW = (unsigned int*)BuS;

    for (int half = 0; half < 2; ++half) {
        __syncthreads();   // BuS free (prev GEMM2 done / first iter: nothing)

        // ---- GEMM1: two 128-wide n-chunks -> BuS (A from hS, B direct from global W1t) ----
        #pragma unroll
        for (int ncl = 0; ncl < 2; ++ncl) {
            const int nc = half * 2 + ncl;
            f32x4 acc1[4][2] = {};
            const unsigned short* Wb = W1t + (size_t)(nc * 128 + wn1 + mrow) * 256 + kq;
            #pragma unroll
            for (int ks = 0; ks < 8; ++ks) {
                const int k0 = ks * 32;
                bf16x8 fb0 = *(const bf16x8*)(Wb + k0);
                bf16x8 fb1 = *(const bf16x8*)(Wb + 16 * 256 + k0);
                bf16x8 fa[4];
                #pragma unroll
                for (int i = 0; i < 4; i++)
                    fa[i] = *(const bf16x8*)&hS[(wm1 + i * 16 + mrow) * HSTR + k0 + kq];
                #pragma unroll
                for (int i = 0; i < 4; i++) {
                    acc1[i][0] = __builtin_amdgcn_mfma_f32_16x16x32_bf16(fa[i], fb0, acc1[i][0], 0, 0, 0);
                    acc1[i][1] = __builtin_amdgcn_mfma_f32_16x16x32_bf16(fa[i], fb1, acc1[i][1], 0, 0, 0);
                }
            }
            #pragma unroll
            for (int i = 0; i < 4; i++)
                #pragma unroll
                for (int j = 0; j < 2; j++)
                    #pragma unroll
                    for (int r = 0; r < 4; r++)
                        BuS[(wm1 + i * 16 + r0 + r) * HSTR + ncl * 128 + wn1 + j * 16 + c0]
                            = f2bf(acc1[i][j][r]);
        }
        __syncthreads();

        // ---- chunk-local scan (zero-seeded), fp32 state, publish final ----
        if (t < 128) {
            const int pg = half * 128 + t;
            float ar = par[2 * pg], ai = par[2 * pg + 1];
            float xr = 0.0f, xi = 0.0f;
            #pragma unroll 8
            for (int j = 0; j < 128; j++) {
                unsigned int v = BuW[j * (HSTR / 2) + t];
                float vr = bf2f(v & 0xFFFFu), vi = bf2f(v >> 16);
                float nr = fmaf(ar, xr, fmaf(-ai, xi, vr));
                float ni = fmaf(ar, xi, fmaf(ai, xr, vi));
                xr = nr; xi = ni;
                BuW[j * (HSTR / 2) + t] = (unsigned int)f2bf(xr) | ((unsigned int)f2bf(xi) << 16);
            }
            union { float f[2]; ull u; } pk; pk.f[0] = xr; pk.f[1] = xi;
            __hip_atomic_store(&Lbuf[(size_t)(half * 256 + blk) * 128 + t], pk.u,
                               __ATOMIC_RELAXED, __HIP_MEMORY_SCOPE_AGENT);
        }
        __syncthreads();
        if (t == 0)
            __hip_atomic_store(&flags[half * 256 + blk], 1,
                               __ATOMIC_RELEASE, __HIP_MEMORY_SCOPE_AGENT);

        // ---- lookback: P = sum_{k<c} A^{128(c-1-k)} * L_k ----
        if (t < 128) {
            const int pg = half * 128 + t;
            float Pr = 0.0f, Pi = 0.0f;
            for (int k = 0; k < c; ++k) {
                const int fi = half * 256 + b * 32 + k;
                while (__hip_atomic_load(&flags[fi], __ATOMIC_ACQUIRE,
                                         __HIP_MEMORY_SCOPE_AGENT) == 0) {}
                union { float f[2]; ull u; } lk;
                lk.u = __hip_atomic_load(&Lbuf[(size_t)fi * 128 + t],
                                         __ATOMIC_RELAXED, __HIP_MEMORY_SCOPE_AGENT);
                const float2 Am = *(const float2*)(Apow + (size_t)(c - 1 - k) * 512 + 2 * pg);
                Pr = fmaf(Am.x, lk.f[0], fmaf(-Am.y, lk.f[1], Pr));
                Pi = fmaf(Am.x, lk.f[1], fmaf(Am.y, lk.f[0], Pi));
            }
            Pp[t] = make_float2(Pr, Pi);
        }
        __syncthreads();

        // ---- apply: x = xloc + a^{j+1} * P  (in LDS, one bf16 re-round) ----
        if (c > 0) {
            const int j = t >> 2, cs = (t & 3) * 32;
            const float2* ap = (const float2*)apw + (size_t)j * 256 + half * 128 + cs;
            #pragma unroll 8
            for (int i = 0; i < 32; i++) {
                float2 a2 = ap[i];
                float2 P  = Pp[cs + i];
                unsigned int v = BuW[j * (HSTR / 2) + cs + i];
                float vr = bf2f(v & 0xFFFFu), vi = bf2f(v >> 16);
                float xr = fmaf(a2.x, P.x, fmaf(-a2.y, P.y, vr));
                float xi = fmaf(a2.x, P.y, fmaf(a2.y, P.x, vi));
                BuW[j * (HSTR / 2) + cs + i] = (unsigned int)f2bf(xr) | ((unsigned int)f2bf(xi) << 16);
            }
        }
        __syncthreads();

        // ---- GEMM2 partial-K accumulate (A from BuS, B direct from global W2t) ----
        {
            const unsigned short* Wb = W2t + (size_t)(wn2 + mrow) * 512 + half * 256 + kq;
            #pragma unroll
            for (int ks = 0; ks < 8; ++ks) {
                const int k0 = ks * 32;
                bf16x8 fb[4];
                #pragma unroll
                for (int j = 0; j < 4; j++)
                    fb[j] = *(const bf16x8*)(Wb + (size_t)j * 16 * 512 + k0);
                bf16x8 fa[4];
                #pragma unroll
                for (int i = 0; i < 4; i++)
                    fa[i] = *(const bf16x8*)&BuS[(wm2 + i * 16 + mrow) * HSTR + k0 + kq];
                #pragma unroll
                for (int i = 0; i < 4; i++)
                    #pragma unroll
                    for (int j = 0; j < 4; j++)
                        acc2[i][j] = __builtin_amdgcn_mfma_f32_16x16x32_bf16(fa[i], fb[j], acc2[i][j], 0, 0, 0);
            }
        }
    }

    // ---- epilogue: out = u + gelu(acc2) ----
    #pragma unroll
    for (int i = 0; i < 4; i++) {
        #pragma unroll
        for (int r = 0; r < 4; r++) {
            const size_t gr = rowbase + wm2 + i * 16 + r0 + r;
            const float* up = u + gr * 256 + wn2 + c0;
            float* op = out + gr * 256 + wn2 + c0;
            #pragma unroll
            for (int j = 0; j < 4; j++) {
                float y = acc2[i][j][r];
                float z = 0.7978845608f * fmaf(0.044715f * y * y, y, y);
                float e = __expf(2.0f * z);
                float th = 1.0f - 2.0f / (e + 1.0f);
                op[j * 16] = up[j * 16] + 0.5f * y * (1.0f + th);
            }
        }
    }
}

extern "C" void kernel_launch(void* const* d_in, const int* in_sizes, int n_in,
                              void* d_out, int out_size, void* d_ws, size_t ws_size,
                              hipStream_t stream) {
    const float* u   = (const float*)d_in[0];
    const float* llr = (const float*)d_in[1];
    const float* lim = (const float*)d_in[2];
    const float* Br  = (const float*)d_in[3];
    const float* Bi  = (const float*)d_in[4];
    const float* Cr  = (const float*)d_in[5];
    const float* Ci  = (const float*)d_in[6];
    const float* ldl = (const float*)d_in[7];
    const float* gam = (const float*)d_in[8];
    const float* bet = (const float*)d_in[9];
    float* out = (float*)d_out;

    char* ws = (char*)d_ws;
    float* par   = (float*)(ws);                 // 2048 B
    float* apw   = (float*)(ws + 2048);          // 128*512*4 = 262144 B
    float* Apow  = (float*)(ws + 266240);        // 32*512*4 = 65536 B
    int*   flags = (int*)  (ws + 331776);        // 2*256*4 = 2048 B
    ull*   Lbuf  = (ull*)  (ws + 335872);        // 2*256*128*8 = 524288 B
    unsigned short* W1t = (unsigned short*)(ws + 860160);   // 262144 B
    unsigned short* W2t = (unsigned short*)(ws + 1122304);  // 262144 B

    hipMemsetAsync(flags, 0, 2 * 256 * sizeof(int), stream);
    params_k<<<1, PDIM, 0, stream>>>(llr, lim, ldl, par, apw, Apow);
    w12_k<<<PDIM, HDIM, 0, stream>>>(Br, Bi, Cr, Ci, llr, lim, ldl, W1t, W2t);

    fused_k<<<BATCH * NCHUNK, 512, 0, stream>>>(u, W1t, W2t, par, apw, Apow,
                                                Lbuf, flags, gam, bet, out);
}

// Round 6
// 177.445 us; speedup vs baseline: 1.7691x; 1.7691x over previous
//
#include <hip/hip_runtime.h>
#include <math.h>

#define HDIM 256
#define PDIM 256
#define BATCH 8
#define LSEQ 4096
#define MTOT (BATCH * LSEQ)   // 32768
#define CHLEN 128             // chunk = one 128-row M-tile
#define NCHUNK 32             // LSEQ / CHLEN

typedef __attribute__((ext_vector_type(8))) short bf16x8;   // 8 bf16 = 4 VGPRs
typedef __attribute__((ext_vector_type(4))) float f32x4;

__device__ __forceinline__ unsigned short f2bf(float f) {
    union { float f; unsigned int u; } v; v.f = f;
    unsigned int r = v.u + 0x7FFFu + ((v.u >> 16) & 1u);   // RNE
    return (unsigned short)(r >> 16);
}
__device__ __forceinline__ float bf2f(unsigned int lo16) {
    union { unsigned int u; float f; } v; v.u = lo16 << 16;
    return v.f;
}

// ---------------- prep: W1t, W2t, par (a), apw[j][2p]=a^{j+1} ----------------
// block = p (256), thread = h (256). Thread 0 additionally fills par/apw for its p.
__global__ void prep_k(const float* __restrict__ Br, const float* __restrict__ Bi,
                       const float* __restrict__ Cr, const float* __restrict__ Ci,
                       const float* __restrict__ llr, const float* __restrict__ lim,
                       const float* __restrict__ ldl,
                       unsigned short* __restrict__ W1t, unsigned short* __restrict__ W2t,
                       float* __restrict__ par, float* __restrict__ apw) {
    int p = blockIdx.x, h = threadIdx.x;
    float er = expf(llr[p]);          // -Re(lam) > 0
    float im = lim[p];
    float d  = expf(ldl[p]);
    float zr = -er * d, zi = im * d;  // lam*delta
    float ea = expf(zr);
    float ar = ea * cosf(zi), ai = ea * sinf(zi);   // a = exp(lam*delta)
    float dr = -er, di = im;
    float den = dr * dr + di * di;
    float nr = ar - 1.0f, ni = ai;
    float cr = (nr * dr + ni * di) / den;           // coef = (a-1)/lam
    float ci = (ni * dr - nr * di) / den;
    float br = Br[p * HDIM + h], bi = Bi[p * HDIM + h];
    W1t[(2 * p) * HDIM + h]     = f2bf(cr * br - ci * bi);
    W1t[(2 * p + 1) * HDIM + h] = f2bf(cr * bi + ci * br);
    W2t[h * 512 + 2 * p]     = f2bf(Cr[h * PDIM + p]);
    W2t[h * 512 + 2 * p + 1] = f2bf(-Ci[h * PDIM + p]);
    if (h == 0) {
        par[2 * p]     = ar;
        par[2 * p + 1] = ai;
        float pr = ar, pi = ai;
        apw[2 * p] = pr; apw[2 * p + 1] = pi;       // a^1
        for (int j = 1; j < CHLEN; j++) {
            float tr = pr * ar - pi * ai;
            float ti = pr * ai + pi * ar;
            pr = tr; pi = ti;
            apw[j * 512 + 2 * p]     = pr;          // a^{j+1}
            apw[j * 512 + 2 * p + 1] = pi;
        }
    }
}

// ---------------- fused LayerNorm -> bf16 h ----------------
__global__ void ln_k(const float* __restrict__ u, unsigned short* __restrict__ hbf,
                     const float* __restrict__ gamma, const float* __restrict__ beta) {
    __shared__ float gS[HDIM], bS[HDIM];
    int t = threadIdx.x;
    gS[t] = gamma[t]; bS[t] = beta[t];
    int lane = t & 63, wv = t >> 6;
    int row = blockIdx.x * 4 + wv;
    float4 v = *(const float4*)(u + (size_t)row * HDIM + lane * 4);
    float s  = v.x + v.y + v.z + v.w;
    float sq = v.x * v.x + v.y * v.y + v.z * v.z + v.w * v.w;
    #pragma unroll
    for (int o = 1; o < 64; o <<= 1) { s += __shfl_xor(s, o); sq += __shfl_xor(sq, o); }
    float mu = s * (1.0f / HDIM);
    float rs = rsqrtf(sq * (1.0f / HDIM) - mu * mu + 1e-5f);
    __syncthreads();
    int c = lane * 4;
    ushort4 o;
    o.x = f2bf((v.x - mu) * rs * gS[c + 0] + bS[c + 0]);
    o.y = f2bf((v.y - mu) * rs * gS[c + 1] + bS[c + 1]);
    o.z = f2bf((v.z - mu) * rs * gS[c + 2] + bS[c + 2]);
    o.w = f2bf((v.w - mu) * rs * gS[c + 3] + bS[c + 3]);
    *(ushort4*)(hbf + (size_t)row * HDIM + c) = o;
}

// ---------------- GEMM1 + chunk-local scan (zero-seeded) ----------------
// Stores xloc[M][512] (locally-scanned Bu) and last[bm][p] = xloc[127] (fp32).
__launch_bounds__(256, 2)
__global__ void gemm1_k(const unsigned short* __restrict__ A, const unsigned short* __restrict__ B,
                        unsigned short* __restrict__ Bu, float* __restrict__ last,
                        const float* __restrict__ par, const float* __restrict__ apw) {
    __shared__ union {
        struct { unsigned short A[128 * 32]; unsigned short B[128 * 32]; } st;  // 16 KB
        unsigned short C[128 * 128];                                            // 32 KB
    } sm;

    const int t = threadIdx.x;
    const int bn = blockIdx.x, bm = blockIdx.y;
    const int lane = t & 63;
    const int wm = ((t >> 6) & 1) * 64;
    const int wn = ((t >> 6) >> 1) * 64;
    const int srow = t >> 1, skoff = (t & 1) * 16;
    const unsigned short* Ap = A + (size_t)(bm * 128 + srow) * 256 + skoff;
    const unsigned short* Bp = B + (size_t)(bn * 128 + srow) * 256 + skoff;
    const int mrow = lane & 15, kq = (lane >> 4) * 8;

    f32x4 acc[4][4] = {};

    for (int k0 = 0; k0 < 256; k0 += 32) {
        uint4 a0 = *(const uint4*)(Ap + k0);
        uint4 a1 = *(const uint4*)(Ap + k0 + 8);
        uint4 b0 = *(const uint4*)(Bp + k0);
        uint4 b1 = *(const uint4*)(Bp + k0 + 8);
        __syncthreads();
        *(uint4*)&sm.st.A[srow * 32 + skoff]     = a0;
        *(uint4*)&sm.st.A[srow * 32 + skoff + 8] = a1;
        *(uint4*)&sm.st.B[srow * 32 + skoff]     = b0;
        *(uint4*)&sm.st.B[srow * 32 + skoff + 8] = b1;
        __syncthreads();
        bf16x8 fa[4], fb[4];
        #pragma unroll
        for (int i = 0; i < 4; i++) {
            fa[i] = *(const bf16x8*)&sm.st.A[(wm + i * 16 + mrow) * 32 + kq];
            fb[i] = *(const bf16x8*)&sm.st.B[(wn + i * 16 + mrow) * 32 + kq];
        }
        #pragma unroll
        for (int i = 0; i < 4; i++)
            #pragma unroll
            for (int j = 0; j < 4; j++)
                acc[i][j] = __builtin_amdgcn_mfma_f32_16x16x32_bf16(fa[i], fb[j], acc[i][j], 0, 0, 0);
    }

    __syncthreads();   // done with st; reuse as C
    const int r0 = (lane >> 4) * 4, c0 = lane & 15;
    #pragma unroll
    for (int i = 0; i < 4; i++)
        #pragma unroll
        for (int j = 0; j < 4; j++)
            #pragma unroll
            for (int r = 0; r < 4; r++)
                sm.C[(wm + i * 16 + r0 + r) * 128 + wn + j * 16 + c0] = f2bf(acc[i][j][r]);
    __syncthreads();

    // zero-seeded local scan over the tile's 128 rows (time), one thread per complex col.
    if (t < 64) {
        int pg = bn * 64 + t;
        float ar = par[2 * pg], ai = par[2 * pg + 1];
        float xr = 0.0f, xi = 0.0f;
        unsigned int* Cw = (unsigned int*)sm.C;
        #pragma unroll 8
        for (int s = 0; s < CHLEN; s++) {
            unsigned int v = Cw[s * 64 + t];
            float vr = bf2f(v & 0xFFFFu), vi = bf2f(v >> 16);
            float nr = fmaf(ar, xr, fmaf(-ai, xi, vr));
            float ni = fmaf(ar, xi, fmaf(ai, xr, vi));
            xr = nr; xi = ni;
            Cw[s * 64 + t] = (unsigned int)f2bf(xr) | ((unsigned int)f2bf(xi) << 16);
        }
        *(float2*)(last + (size_t)(bm * 256 + pg) * 2) = make_float2(xr, xi);  // fp32 chunk final
    }
    __syncthreads();

    // coalesced store of the scanned tile (xloc) to Bu
    {
        int row = t >> 1, ch = (t & 1) * 64;
        unsigned short* dst = Bu + (size_t)(bm * 128 + row) * 512 + bn * 128 + ch;
        const unsigned short* src = &sm.C[row * 128 + ch];
        #pragma unroll
        for (int q = 0; q < 8; q++)
            *(uint4*)(dst + q * 8) = *(const uint4*)(src + q * 8);
    }
}

// ---------------- carry across chunks; prefix[bm][p] = state entering chunk ----------------
__global__ void carry_k(const float* __restrict__ last, float* __restrict__ prefix,
                        const float* __restrict__ apw) {
    int p = threadIdx.x, b = blockIdx.x;
    float Ar = apw[127 * 512 + 2 * p], Ai = apw[127 * 512 + 2 * p + 1];  // a^128
    float Pr = 0.0f, Pi = 0.0f;
    for (int c = 0; c < NCHUNK; c++) {
        size_t idx = (size_t)((b * NCHUNK + c) * 256 + p) * 2;
        *(float2*)(prefix + idx) = make_float2(Pr, Pi);
        float2 l = *(const float2*)(last + idx);
        float nr = fmaf(Ar, Pr, fmaf(-Ai, Pi, l.x));
        float ni = fmaf(Ar, Pi, fmaf(Ai, Pr, l.y));
        Pr = nr; Pi = ni;
    }
}

// ---------------- apply: x = xloc + a^{j+1}*prefix (in place on Bu, bf16) ----------------
// grid (NCHUNK, BATCH), 512 threads: k = t&255 (complex col), j-half = t>>8.
__global__ void apply_k(unsigned short* __restrict__ Bu, const float* __restrict__ apw,
                        const float* __restrict__ prefix) {
    int c = blockIdx.x;
    if (c == 0) return;   // prefix is zero
    int b = blockIdx.y;
    int t = threadIdx.x;
    int k = t & 255;
    int j0 = (t >> 8) * 64;
    float2 P = *(const float2*)(prefix + ((size_t)(b * NCHUNK + c) * 256 + k) * 2);
    unsigned int* q = (unsigned int*)(Bu + ((size_t)b * LSEQ + (size_t)c * CHLEN + j0) * 512) + k;
    const float2* ap = (const float2*)apw + (size_t)j0 * 256 + k;
    #pragma unroll 4
    for (int j = 0; j < 64; j++) {
        float2 a2 = ap[(size_t)j * 256];
        unsigned int v = q[(size_t)j * 256];
        float vr = bf2f(v & 0xFFFFu), vi = bf2f(v >> 16);
        float xr = fmaf(a2.x, P.x, fmaf(-a2.y, P.y, vr));
        float xi = fmaf(a2.x, P.y, fmaf(a2.y, P.x, vi));
        q[(size_t)j * 256] = (unsigned int)f2bf(xr) | ((unsigned int)f2bf(xi) << 16);
    }
}

// ---------------- clean GEMM2 + gelu epilogue ----------------
// out[M][256] = u + gelu( x[M][512] @ W2t^T )
#define LDK 40   // padded LDS row stride (elements)
__launch_bounds__(256, 2)
__global__ void gemm2_k(const unsigned short* __restrict__ A, const unsigned short* __restrict__ B,
                        float* __restrict__ out, const float* __restrict__ u) {
    __shared__ unsigned short As[128 * LDK];
    __shared__ unsigned short Bs[128 * LDK];
    const int t = threadIdx.x;
    const int bn = blockIdx.x, bm = blockIdx.y;
    const int lane = t & 63;
    const int wm = ((t >> 6) & 1) * 64;
    const int wn = ((t >> 6) >> 1) * 64;
    const int srow = t >> 1, skoff = (t & 1) * 16;
    const unsigned short* Ap = A + (size_t)(bm * 128 + srow) * 512 + skoff;
    const unsigned short* Bp = B + (size_t)(bn * 128 + srow) * 512 + skoff;
    unsigned short* AsW = &As[srow * LDK + skoff];
    unsigned short* BsW = &Bs[srow * LDK + skoff];
    const int mrow = lane & 15, kq = (lane >> 4) * 8;

    f32x4 acc[4][4] = {};

    for (int k0 = 0; k0 < 512; k0 += 32) {
        uint4 a0 = *(const uint4*)(Ap + k0);
        uint4 a1 = *(const uint4*)(Ap + k0 + 8);
        uint4 b0 = *(const uint4*)(Bp + k0);
        uint4 b1 = *(const uint4*)(Bp + k0 + 8);
        __syncthreads();
        *(uint4*)AsW       = a0;
        *(uint4*)(AsW + 8) = a1;
        *(uint4*)BsW       = b0;
        *(uint4*)(BsW + 8) = b1;
        __syncthreads();
        bf16x8 fa[4], fb[4];
        #pragma unroll
        for (int i = 0; i < 4; i++) {
            fa[i] = *(const bf16x8*)&As[(wm + i * 16 + mrow) * LDK + kq];
            fb[i] = *(const bf16x8*)&Bs[(wn + i * 16 + mrow) * LDK + kq];
        }
        #pragma unroll
        for (int i = 0; i < 4; i++)
            #pragma unroll
            for (int j = 0; j < 4; j++)
                acc[i][j] = __builtin_amdgcn_mfma_f32_16x16x32_bf16(fa[i], fb[j], acc[i][j], 0, 0, 0);
    }

    const int r0 = (lane >> 4) * 4, c0 = lane & 15;
    #pragma unroll
    for (int i = 0; i < 4; i++) {
        #pragma unroll
        for (int r = 0; r < 4; r++) {
            const size_t rowoff = (size_t)(bm * 128 + wm + i * 16 + r0 + r) * 256;
            #pragma unroll
            for (int j = 0; j < 4; j++) {
                const int col = bn * 128 + wn + j * 16 + c0;
                float y = acc[i][j][r];
                float z = 0.7978845608f * fmaf(0.044715f * y * y, y, y);
                float e = __expf(2.0f * z);
                float th = 1.0f - 2.0f / (e + 1.0f);
                out[rowoff + col] = u[rowoff + col] + 0.5f * y * (1.0f + th);
            }
        }
    }
}

extern "C" void kernel_launch(void* const* d_in, const int* in_sizes, int n_in,
                              void* d_out, int out_size, void* d_ws, size_t ws_size,
                              hipStream_t stream) {
    const float* u   = (const float*)d_in[0];
    const float* llr = (const float*)d_in[1];
    const float* lim = (const float*)d_in[2];
    const float* Br  = (const float*)d_in[3];
    const float* Bi  = (const float*)d_in[4];
    const float* Cr  = (const float*)d_in[5];
    const float* Ci  = (const float*)d_in[6];
    const float* ldl = (const float*)d_in[7];
    const float* gam = (const float*)d_in[8];
    const float* bet = (const float*)d_in[9];
    float* out = (float*)d_out;

    float* ws     = (float*)d_ws;
    float* par    = ws;                                   // 1024 floats (a)
    float* apw    = ws + 1024;                            // 128*512 floats (a^{j+1})
    float* last   = apw + 128 * 512;                      // 256*256*2 floats
    float* prefix = last + 256 * 256 * 2;                 // 256*256*2 floats
    unsigned short* W1t = (unsigned short*)(prefix + 256 * 256 * 2);
    unsigned short* W2t = W1t + 512 * HDIM;
    unsigned short* hbf = W2t + HDIM * 512;               // [32768][256] bf16
    unsigned short* Bu  = hbf + (size_t)MTOT * HDIM;      // [32768][512] bf16 (xloc -> x)

    prep_k<<<PDIM, HDIM, 0, stream>>>(Br, Bi, Cr, Ci, llr, lim, ldl, W1t, W2t, par, apw);
    ln_k<<<MTOT / 4, 256, 0, stream>>>(u, hbf, gam, bet);

    // GEMM1 + zero-seeded chunk scan: Bu = localscan(h @ W1t^T), last = chunk finals
    gemm1_k<<<dim3(4, MTOT / 128), 256, 0, stream>>>(hbf, W1t, Bu, last, par, apw);

    carry_k<<<BATCH, PDIM, 0, stream>>>(last, prefix, apw);

    // apply prefix: Bu <- xloc + a^{j+1} * prefix  (skip chunk 0)
    apply_k<<<dim3(NCHUNK, BATCH), 512, 0, stream>>>(Bu, apw, prefix);

    // clean GEMM2 + gelu: out = u + gelu(x @ W2t^T)
    gemm2_k<<<dim3(2, MTOT / 128), 256, 0, stream>>>(Bu, W2t, out, u);
}